// Round 8
// baseline (555.364 us; speedup 1.0000x reference)
//
#include <hip/hip_runtime.h>
#include <stdint.h>

#define N_NODES 20000
#define N_EDGES 320000
#define C 128
#define H 8
#define D 16
#define SLOT 64        // max degree per node per relation (Poisson(16); P(>=64)~1e-18, guarded)
#define NRANGE 5000    // node_p2 ranges of 4 dsts
#define BUCKETS 2500   // 8-dst buckets per relation (20000/8)
#define BCAP 224       // records per (rel,bucket); mean 128, sigma 11.3, P(>224)~1e-13, guarded

// prep_k job partition (block ranges)
#define P_CVT 2500     // 2500*256*4 == N_NODES*C
#define P_ZERO 157     // 4*2500*16 ints = 160000 ints = 40000 int4
#define P_PACK 128
#define P_FUSE 32
// mega_k: 80 part blocks (16K edges each, counting-sort) + 3130 proj blocks.
#define PB_EDGES 16384
#define PART_BLOCKS 80
#define PROJ_BLOCKS 3130
#define MB_TOTAL (PART_BLOCKS + PROJ_BLOCKS)

typedef short s16x8 __attribute__((ext_vector_type(8)));
typedef float f32x4 __attribute__((ext_vector_type(4)));

__device__ __forceinline__ unsigned short f2bf(float f) {
    unsigned int b = __float_as_uint(f);
    b += 0x7fffu + ((b >> 16) & 1u);
    return (unsigned short)(b >> 16);
}
__device__ __forceinline__ float bf2f(unsigned int u) {
    return __uint_as_float(u << 16);
}
__device__ __forceinline__ float bf_lo(unsigned int u) {   // low bf16 of a dword -> f32 (1 instr)
    return __uint_as_float(u << 16);
}
__device__ __forceinline__ float bf_hi(unsigned int u) {   // high bf16 of a dword -> f32 (1 instr)
    return __uint_as_float(u & 0xffff0000u);
}

// ---------------- prep: cvt_h + zero-cursors + pack_wt + fuse_w in ONE dispatch ----------------
__global__ __launch_bounds__(256) void prep_k(const float* __restrict__ h_a, const float* __restrict__ h_b,
                                              unsigned short* __restrict__ oa, unsigned short* __restrict__ ob,
                                              const float* __restrict__ Wq, const float* __restrict__ Wa,
                                              unsigned short* __restrict__ Wqt, unsigned short* __restrict__ Wat,
                                              const float* __restrict__ Wk, const float* __restrict__ Wv,
                                              const float* __restrict__ bk, const float* __restrict__ bv,
                                              const float* __restrict__ att, const float* __restrict__ msg,
                                              unsigned short* __restrict__ Wkt, unsigned short* __restrict__ Wvt,
                                              float* __restrict__ bkt, float* __restrict__ bvt,
                                              int* __restrict__ cur) {
    __shared__ float sa[D * D], sm[D * D];
    int bid = blockIdx.x;
    int tid = threadIdx.x;
    if (bid < P_CVT) {
        int i = (bid * 256 + tid) * 4;
        float4 va = *(const float4*)(h_a + i);
        float4 vb = *(const float4*)(h_b + i);
        ushort4 ua = { f2bf(va.x), f2bf(va.y), f2bf(va.z), f2bf(va.w) };
        ushort4 ub = { f2bf(vb.x), f2bf(vb.y), f2bf(vb.z), f2bf(vb.w) };
        *(ushort4*)(oa + i) = ua;
        *(ushort4*)(ob + i) = ub;
        return;
    }
    bid -= P_CVT;
    if (bid < P_ZERO) {
        int i = bid * 256 + tid;
        if (i < 40000) ((int4*)cur)[i] = make_int4(0, 0, 0, 0);
        return;
    }
    bid -= P_ZERO;
    if (bid < P_PACK) {
        int n = bid;
        int t = tid >> 7, i = tid & 127;
        Wqt[(t * C + n) * C + i] = f2bf(Wq[(t * C + i) * C + n]);
        Wat[(t * C + n) * C + i] = f2bf(Wa[(t * C + i) * C + n]);
        return;
    }
    bid -= P_PACK;
    {
        int r = bid >> 3, h = bid & 7;
        int t = r >> 1;
        if (tid < D * D) {
            sa[tid] = att[(r * H + h) * D * D + tid];
            sm[tid] = msg[(r * H + h) * D * D + tid];
        }
        __syncthreads();
        int i = tid & 127;
        for (int e = (tid >> 7); e < D; e += 2) {
            float sk = 0.f, sv = 0.f;
            for (int d = 0; d < D; ++d) {
                sk += Wk[(t * C + i) * C + h * D + d] * sa[d * D + e];
                sv += Wv[(t * C + i) * C + h * D + d] * sm[d * D + e];
            }
            Wkt[(r * C + h * D + e) * C + i] = f2bf(sk);
            Wvt[(r * C + h * D + e) * C + i] = f2bf(sv);
        }
        if (tid < D) {
            int e = tid;
            float sk = 0.f, sv = 0.f;
            for (int d = 0; d < D; ++d) {
                sk += bk[t * C + h * D + d] * sa[d * D + e];
                sv += bv[t * C + h * D + d] * sm[d * D + e];
            }
            bkt[r * C + h * D + e] = sk;
            bvt[r * C + h * D + e] = sv;
        }
    }
}

// ---------------- mega: edge partition (counting-sort) || projections ----------------
// Partition as block-local counting sort: LDS histogram over 2500 8-dst
// buckets, ONE global atomic per touched bucket per block, then chunked
// 4B-record writes into reserved contiguous chunks.
__global__ __launch_bounds__(256) void mega_k(const int* __restrict__ s0, const int* __restrict__ s1,
                                              const int* __restrict__ s2, const int* __restrict__ s3,
                                              const int* __restrict__ d0, const int* __restrict__ d1,
                                              const int* __restrict__ d2, const int* __restrict__ d3,
                                              int* __restrict__ cur, unsigned int* __restrict__ part,
                                              const unsigned short* __restrict__ ha,
                                              const unsigned short* __restrict__ hb,
                                              const unsigned short* __restrict__ Wqt,
                                              const unsigned short* __restrict__ Wkt,
                                              const unsigned short* __restrict__ Wvt,
                                              const float* __restrict__ bq,
                                              const float* __restrict__ bkt,
                                              const float* __restrict__ bvt,
                                              unsigned short* __restrict__ Qa,
                                              unsigned short* __restrict__ Qb,
                                              unsigned short* __restrict__ Kall,
                                              unsigned short* __restrict__ Vall) {
    __shared__ int hcnt[BUCKETS];
    __shared__ int hbase[BUCKETS];
    int bid = blockIdx.x;
    int tid = threadIdx.x;

    if (bid < PART_BLOCKS) {
        // ---- partition path: counting-sort of 16K edges into 8-dst buckets ----
        int r  = bid & 3;
        int pb = bid >> 2;                       // 0..19
        int start = pb * PB_EDGES;
        int nval = N_EDGES - start;
        if (nval > PB_EDGES) nval = PB_EDGES;    // last block: 8704
        int nq = nval >> 2;                      // int4 count (both tails %4==0)
        const int* dd = (r == 0) ? d0 : (r == 1) ? d1 : (r == 2) ? d2 : d3;
        const int* ss = (r == 0) ? s0 : (r == 1) ? s1 : (r == 2) ? s2 : s3;
        for (int b = tid; b < BUCKETS; b += 256) hcnt[b] = 0;
        __syncthreads();
        // pass A: LDS histogram
        for (int i = tid; i < nq; i += 256) {
            int4 d4 = *(const int4*)(dd + start + i * 4);
            atomicAdd(&hcnt[d4.x >> 3], 1);
            atomicAdd(&hcnt[d4.y >> 3], 1);
            atomicAdd(&hcnt[d4.z >> 3], 1);
            atomicAdd(&hcnt[d4.w >> 3], 1);
        }
        __syncthreads();
        // reserve contiguous chunks: one global atomic per touched bucket
        for (int b = tid; b < BUCKETS; b += 256) {
            int c = hcnt[b];
            hbase[b] = c ? atomicAdd(&cur[(r * BUCKETS + b) * 16], c) : 0;
            hcnt[b] = 0;                         // reuse as pass-B cursor
        }
        __syncthreads();
        // pass B: scatter 4B records into reserved chunks
        for (int i = tid; i < nq; i += 256) {
            int4 d4 = *(const int4*)(dd + start + i * 4);
            int4 s4 = *(const int4*)(ss + start + i * 4);
            int b0 = d4.x >> 3, b1 = d4.y >> 3, b2 = d4.z >> 3, b3 = d4.w >> 3;
            int i0 = atomicAdd(&hcnt[b0], 1);
            int i1 = atomicAdd(&hcnt[b1], 1);
            int i2 = atomicAdd(&hcnt[b2], 1);
            int i3 = atomicAdd(&hcnt[b3], 1);
            int p0 = hbase[b0] + i0, p1 = hbase[b1] + i1, p2 = hbase[b2] + i2, p3 = hbase[b3] + i3;
            if (p0 < BCAP) part[(size_t)(r * BUCKETS + b0) * BCAP + p0] = (unsigned int)s4.x | ((unsigned int)(d4.x & 7) << 15);
            if (p1 < BCAP) part[(size_t)(r * BUCKETS + b1) * BCAP + p1] = (unsigned int)s4.y | ((unsigned int)(d4.y & 7) << 15);
            if (p2 < BCAP) part[(size_t)(r * BUCKETS + b2) * BCAP + p2] = (unsigned int)s4.z | ((unsigned int)(d4.z & 7) << 15);
            if (p3 < BCAP) part[(size_t)(r * BUCKETS + b3) * BCAP + p3] = (unsigned int)s4.w | ((unsigned int)(d4.w & 7) << 15);
        }
        return;
    }
    // ---- projection path: 10 jobs x 313 blocks ----
    int proj_id = bid - PART_BLOCKS;
    int j = proj_id / 313;
    int xb = proj_id - j * 313;
    const unsigned short* A;
    const unsigned short* Wt;
    const float* bias;
    unsigned short* Out;
    if (j < 2) {
        A = j ? hb : ha; Wt = Wqt + j * C * C; bias = bq + j * C; Out = j ? Qb : Qa;
    } else if (j < 6) {
        int r = j - 2;
        A = (r < 2) ? ha : hb; Wt = Wkt + r * C * C; bias = bkt + r * C;
        Out = Kall + (size_t)r * N_NODES * C;
    } else {
        int r = j - 6;
        A = (r < 2) ? ha : hb; Wt = Wvt + r * C * C; bias = bvt + r * C;
        Out = Vall + (size_t)r * N_NODES * C;
    }
    int wid = threadIdx.x >> 6, l = threadIdx.x & 63;
    int row_base = xb * 64 + wid * 16;
    int lm = l & 15, q = l >> 4;
    f32x4 acc[8] = {};
    int arow = row_base + lm;
    if (arow >= N_NODES) arow = N_NODES - 1;
    const s16x8* Ap = (const s16x8*)(A + (size_t)arow * C);
#pragma unroll
    for (int kc = 0; kc < 4; ++kc) {
        s16x8 af = Ap[kc * 4 + q];
#pragma unroll
        for (int t = 0; t < 8; ++t) {
            s16x8 bf = *(const s16x8*)(Wt + (t * 16 + lm) * C + kc * 32 + q * 8);
            acc[t] = __builtin_amdgcn_mfma_f32_16x16x32_bf16(af, bf, acc[t], 0, 0, 0);
        }
    }
#pragma unroll
    for (int t = 0; t < 8; ++t) {
        int col = t * 16 + lm;
        float b = bias[col];
#pragma unroll
        for (int i = 0; i < 4; ++i) {
            int row = row_base + q * 4 + i;
            if (row < N_NODES) Out[(size_t)row * C + col] = f2bf(acc[t][i] + b);
        }
    }
}

// ---------------- P2: bucket-scan + LDS-bin + scoring/softmax/aggregate + FUSED OUTPUT ----------------
// Main loop is byte-identical to R7 (scalar floats — R6's collapse is attributed
// to the f32x2 ext-vector rewrite hitting runtime-indexed-array scratch spill,
// NOT the epilogue). One block per (type, 4 dsts); ONE dst per wave; 4 edge-
// groups of 16 lanes, 8 ch/lane, dwordx4 gathers; XCD type-partitioned grid.
// FUSED EPILOGUE (replaces final_mm): merged f32 out[8] -> 2KB LDS agg rows ->
// each thread computes 2 output cols as a 128-dot vs L2-hot Wat + skip-gate.
// Kills a dispatch + the 10MB agg write + 10MB agg read.
__global__ __launch_bounds__(256) void node_p2(const int* __restrict__ cur,
                                               const unsigned int* __restrict__ part,
                                               const unsigned int* __restrict__ Kall,
                                               const unsigned int* __restrict__ Vall,
                                               const float* __restrict__ pri,
                                               const unsigned int* __restrict__ Qa,
                                               const unsigned int* __restrict__ Qb,
                                               const unsigned short* __restrict__ WatAll,
                                               const float* __restrict__ baAll,
                                               const float* __restrict__ skip,
                                               const float* __restrict__ h_a,
                                               const float* __restrict__ h_b,
                                               float* __restrict__ OutAll) {
    __shared__ unsigned short slot[2][4][SLOT];
    __shared__ int cnt[2][4];
    __shared__ __align__(16) float aggl[4][C];   // 4 nodes x 128 ch f32 (2 KB)
    int g = blockIdx.x;
    int xcd = g & 7, idx = g >> 3;     // round-robin XCD id, slot within XCD
    int type = xcd >> 2;               // xcd 0-3 -> type 0, xcd 4-7 -> type 1
    int range = (xcd & 3) * 1250 + idx; // 4 XCDs x 1250 = 5000 ranges per type
    int relA = type ? 1 : 0;           // ab : aa
    int relB = type ? 3 : 2;           // bb : ba
    if (threadIdx.x < 8) ((int*)cnt)[threadIdx.x] = 0;
    __syncthreads();
    int bkt = range >> 1;              // 8-dst bucket containing this range
    int w   = range & 1;               // 4-dst window within the bucket
#pragma unroll
    for (int rr = 0; rr < 2; ++rr) {
        int rel = rr ? relB : relA;
        int c = cur[(rel * BUCKETS + bkt) * 16];
        if (c > BCAP) c = BCAP;
        const unsigned int* pp = part + (size_t)(rel * BUCKETS + bkt) * BCAP;
        for (int i = threadIdx.x; i < c; i += 256) {
            unsigned int rec = pp[i];
            int dlow = (rec >> 15) & 7;
            if ((dlow >> 2) == w) {
                int dof = dlow & 3;
                int p = atomicAdd(&cnt[rr][dof], 1);
                if (p < SLOT) slot[rr][dof][p] = (unsigned short)(rec & 0x7fffu);
            }
        }
    }
    __syncthreads();

    int wid = threadIdx.x >> 6, l = threadIdx.x & 63;
    int eg = l >> 4;                    // edge-group 0..3 (4 edges in flight per wave)
    int j  = l & 15;                    // channel-lane: owns channels 8j..8j+7
    int hg = j >> 1;                    // head = 16 ch = 2 lanes
    int dof = wid;                      // ONE dst per wave
    int n = range * 4 + dof;
    const unsigned int* Q32 = type ? Qb : Qa;
    uint4 qv = *(const uint4*)(Q32 + (size_t)n * 64 + j * 4);
    float q0 = bf_lo(qv.x), q1 = bf_hi(qv.x), q2 = bf_lo(qv.y), q3 = bf_hi(qv.y);
    float q4 = bf_lo(qv.z), q5 = bf_hi(qv.z), q6 = bf_lo(qv.w), q7 = bf_hi(qv.w);
    float out[8] = {};

#pragma unroll 1
    for (int rr = 0; rr < 2; ++rr) {
        int rel = rr ? relB : relA;
        const char* Kb = (const char*)(Kall + (size_t)rel * N_NODES * 64);
        const char* Vb = (const char*)(Vall + (size_t)rel * N_NODES * 64);
        float pv = pri[rel * 8 + hg] * 0.25f;
        int deg = cnt[rr][dof];
        if (deg > SLOT) deg = SLOT;
        float m = -1e30f, sum = 0.f;
        float acc[8] = {};
        for (int base = 0; base < deg; base += 16) {   // 16 edges/chunk = 4 per edge-group
            float s[4];
            uint4 vv[4];
#pragma unroll
            for (int i = 0; i < 4; ++i) {
                int idx2 = base + i * 4 + eg;          // interleaved -> balanced tails
                float d = -1e30f;
                uint4 v = {0u, 0u, 0u, 0u};
                if (idx2 < deg) {
                    // 32-bit voffset: sv*256B row + j*16B -> sgpr-base + voffset loads
                    unsigned off = ((unsigned)slot[rr][dof][idx2] << 8) | ((unsigned)j << 4);
                    uint4 kv = *(const uint4*)(Kb + off);
                    v = *(const uint4*)(Vb + off);     // fetched with K (indep of max)
                    d = q0 * bf_lo(kv.x) + q1 * bf_hi(kv.x)
                      + q2 * bf_lo(kv.y) + q3 * bf_hi(kv.y)
                      + q4 * bf_lo(kv.z) + q5 * bf_hi(kv.z)
                      + q6 * bf_lo(kv.w) + q7 * bf_hi(kv.w);
                    d += __shfl_xor(d, 1);             // full 16-ch head dot in both lanes
                    d *= pv;
                }
                s[i] = d;
                vv[i] = v;
            }
            float mloc = fmaxf(fmaxf(s[0], s[1]), fmaxf(s[2], s[3]));
            float mnew = fmaxf(m, mloc);
            float alpha = __expf(m - mnew);            // first chunk: exp(-huge)=0
            sum *= alpha;
#pragma unroll
            for (int c2 = 0; c2 < 8; ++c2) acc[c2] *= alpha;
            m = mnew;
#pragma unroll
            for (int i = 0; i < 4; ++i) {
                // guard: an all-invalid group has m==-1e30 -> exp(0)==1 would leak
                float ww = (s[i] > -1e29f) ? __expf(s[i] - m) : 0.f;
                sum += ww;
                acc[0] += ww * bf_lo(vv[i].x); acc[1] += ww * bf_hi(vv[i].x);
                acc[2] += ww * bf_lo(vv[i].y); acc[3] += ww * bf_hi(vv[i].y);
                acc[4] += ww * bf_lo(vv[i].z); acc[5] += ww * bf_hi(vv[i].z);
                acc[6] += ww * bf_lo(vv[i].w); acc[7] += ww * bf_hi(vv[i].w);
            }
        }
        // merge the 4 edge-group partials (butterfly over lane bits 4,5):
        // global max, rescale each group's state by exp(m-m_all), plain-sum.
        float m1 = fmaxf(m, __shfl_xor(m, 16));
        float m2 = fmaxf(m1, __shfl_xor(m1, 32));
        float beta = __expf(m - m2);                   // empty group: exp(-huge)=0
        sum *= beta;
        sum += __shfl_xor(sum, 16);
        sum += __shfl_xor(sum, 32);
#pragma unroll
        for (int c2 = 0; c2 < 8; ++c2) {
            float a = acc[c2] * beta;
            a += __shfl_xor(a, 16);
            a += __shfl_xor(a, 32);
            acc[c2] = a;
        }
        if (deg > 0) {
            float rs = 1.f / sum;
#pragma unroll
            for (int c2 = 0; c2 < 8; ++c2) out[c2] += acc[c2] * rs;
        }
    }
    // ---- stage f32 agg rows in LDS (0.5 = cross_reducer 'mean'); after the
    // butterfly every lane holds the merged result for its j-channels ----
    if (eg == 0) {
#pragma unroll
        for (int c2 = 0; c2 < 8; ++c2) aggl[dof][j * 8 + c2] = 0.5f * out[c2];
    }
    __syncthreads();
    // ---- fused final (was final_mm): Out = al*(agg @ Wa + ba) + (1-al)*h ----
    // 512 outputs (4 nodes x 128 cols), 2 per thread; nd uniform per wave ->
    // aggl reads are LDS broadcasts; Wat rows are L2-hot (32KB per type).
    {
        const unsigned short* Wt = WatAll + type * C * C;
        const float* bat = baAll + type * C;
        const float* horig = type ? h_b : h_a;
        float* Outp = OutAll + (size_t)type * N_NODES * C;
        float al = 1.f / (1.f + __expf(-skip[type]));
#pragma unroll
        for (int it = 0; it < 2; ++it) {
            int e = it * 256 + threadIdx.x;
            int nd = e >> 7, col = e & 127;
            int node = range * 4 + nd;
            const uint4* w4 = (const uint4*)(Wt + (size_t)col * C);  // Wat row col = Wa col
            const float4* ag4 = (const float4*)aggl[nd];
            float acc = 0.f;
#pragma unroll
            for (int kc = 0; kc < 16; ++kc) {
                uint4 wv = w4[kc];
                float4 a0 = ag4[kc * 2];
                float4 a1 = ag4[kc * 2 + 1];
                acc += a0.x * bf_lo(wv.x) + a0.y * bf_hi(wv.x)
                     + a0.z * bf_lo(wv.y) + a0.w * bf_hi(wv.y)
                     + a1.x * bf_lo(wv.z) + a1.y * bf_hi(wv.z)
                     + a1.z * bf_lo(wv.w) + a1.w * bf_hi(wv.w);
            }
            Outp[(size_t)node * C + col] =
                al * (acc + bat[col]) + (1.f - al) * horig[(size_t)node * C + col];
        }
    }
}

extern "C" void kernel_launch(void* const* d_in, const int* in_sizes, int n_in,
                              void* d_out, int out_size, void* d_ws, size_t ws_size,
                              hipStream_t stream) {
    const float* h_a  = (const float*)d_in[0];
    const float* h_b  = (const float*)d_in[1];
    const float* Wk   = (const float*)d_in[2];
    const float* bk   = (const float*)d_in[3];
    const float* Wq   = (const float*)d_in[4];
    const float* bq   = (const float*)d_in[5];
    const float* Wv   = (const float*)d_in[6];
    const float* bv   = (const float*)d_in[7];
    const float* Wa   = (const float*)d_in[8];
    const float* ba   = (const float*)d_in[9];
    const float* att  = (const float*)d_in[10];
    const float* msg  = (const float*)d_in[11];
    const float* pri  = (const float*)d_in[12];
    const float* skip = (const float*)d_in[13];
    const int* srcs[4] = {(const int*)d_in[14], (const int*)d_in[16], (const int*)d_in[18], (const int*)d_in[20]};
    const int* dsts[4] = {(const int*)d_in[15], (const int*)d_in[17], (const int*)d_in[19], (const int*)d_in[21]};
    float* out = (float*)d_out;

    char* w = (char*)d_ws;
    auto alloc = [&](size_t bytes) {
        char* p = w;
        w += (bytes + 255) & ~(size_t)255;
        return p;
    };
    unsigned short* ha_bf = (unsigned short*)alloc((size_t)N_NODES * C * 2);
    unsigned short* hb_bf = (unsigned short*)alloc((size_t)N_NODES * C * 2);
    unsigned short* Qa    = (unsigned short*)alloc((size_t)N_NODES * C * 2);
    unsigned short* Qb    = (unsigned short*)alloc((size_t)N_NODES * C * 2);
    unsigned short* Kall  = (unsigned short*)alloc((size_t)4 * N_NODES * C * 2);
    unsigned short* Vall  = (unsigned short*)alloc((size_t)4 * N_NODES * C * 2);
    unsigned short* Wqt   = (unsigned short*)alloc(2 * C * C * 2);
    unsigned short* Wat   = (unsigned short*)alloc(2 * C * C * 2);
    unsigned short* Wkt   = (unsigned short*)alloc(4 * C * C * 2);
    unsigned short* Wvt   = (unsigned short*)alloc(4 * C * C * 2);
    float* bkt            = (float*)alloc(4 * C * 4);
    float* bvt            = (float*)alloc(4 * C * 4);
    int* cur              = (int*)alloc((size_t)4 * BUCKETS * 16 * 4);
    unsigned int* part    = (unsigned int*)alloc((size_t)4 * BUCKETS * BCAP * 4);

    // 1) fused prep: cvt + zero-cursors + pack + fuse
    prep_k<<<P_CVT + P_ZERO + P_PACK + P_FUSE, 256, 0, stream>>>(
        h_a, h_b, ha_bf, hb_bf, Wq, Wa, Wqt, Wat,
        Wk, Wv, bk, bv, att, msg, Wkt, Wvt, bkt, bvt, cur);

    // 2) fused partition (counting-sort) || projections
    mega_k<<<MB_TOTAL, 256, 0, stream>>>(
        srcs[0], srcs[1], srcs[2], srcs[3],
        dsts[0], dsts[1], dsts[2], dsts[3],
        cur, part,
        ha_bf, hb_bf, Wqt, Wkt, Wvt, bq, bkt, bvt,
        Qa, Qb, Kall, Vall);

    // 3) fused scoring + softmax + aggregate + OUTPUT PROJECTION (final_mm fused)
    node_p2<<<2 * NRANGE, 256, 0, stream>>>(cur, part,
                                            (const unsigned int*)Kall, (const unsigned int*)Vall,
                                            pri,
                                            (const unsigned int*)Qa, (const unsigned int*)Qb,
                                            Wat, ba, skip, h_a, h_b, out);
}

// Round 9
// 393.531 us; speedup vs baseline: 1.4112x; 1.4112x over previous
//
#include <hip/hip_runtime.h>
#include <stdint.h>

#define N_NODES 20000
#define N_EDGES 320000
#define C 128
#define H 8
#define D 16
#define SLOT 64        // max degree per node per relation (Poisson(16); P(>=64)~1e-18, guarded)
#define NRANGE 5000    // node_p2 ranges of 4 dsts
#define BUCKETS 2500   // 8-dst buckets per relation (20000/8)
#define BCAP 224       // records per (rel,bucket); mean 128, sigma 11.3, P(>224)~1e-13, guarded

// prep_k job partition (block ranges)
#define P_CVT 2500     // 2500*256*4 == N_NODES*C
#define P_ZERO 157     // 4*2500*16 ints = 160000 ints = 40000 int4
#define P_PACK 128
#define P_FUSE 32
// mega_k: 80 part blocks (16K edges each, counting-sort) + 3130 proj blocks.
#define PB_EDGES 16384
#define PART_BLOCKS 80
#define PROJ_BLOCKS 3130
#define MB_TOTAL (PART_BLOCKS + PROJ_BLOCKS)

typedef short s16x8 __attribute__((ext_vector_type(8)));
typedef float f32x4 __attribute__((ext_vector_type(4)));

__device__ __forceinline__ unsigned short f2bf(float f) {
    unsigned int b = __float_as_uint(f);
    b += 0x7fffu + ((b >> 16) & 1u);
    return (unsigned short)(b >> 16);
}
__device__ __forceinline__ float bf2f(unsigned int u) {
    return __uint_as_float(u << 16);
}
__device__ __forceinline__ float bf_lo(unsigned int u) {   // low bf16 of a dword -> f32 (1 instr)
    return __uint_as_float(u << 16);
}
__device__ __forceinline__ float bf_hi(unsigned int u) {   // high bf16 of a dword -> f32 (1 instr)
    return __uint_as_float(u & 0xffff0000u);
}

// ---------------- prep: cvt_h + zero-cursors + pack_wt + fuse_w in ONE dispatch ----------------
__global__ __launch_bounds__(256) void prep_k(const float* __restrict__ h_a, const float* __restrict__ h_b,
                                              unsigned short* __restrict__ oa, unsigned short* __restrict__ ob,
                                              const float* __restrict__ Wq, const float* __restrict__ Wa,
                                              unsigned short* __restrict__ Wqt, unsigned short* __restrict__ Wat,
                                              const float* __restrict__ Wk, const float* __restrict__ Wv,
                                              const float* __restrict__ bk, const float* __restrict__ bv,
                                              const float* __restrict__ att, const float* __restrict__ msg,
                                              unsigned short* __restrict__ Wkt, unsigned short* __restrict__ Wvt,
                                              float* __restrict__ bkt, float* __restrict__ bvt,
                                              int* __restrict__ cur) {
    __shared__ float sa[D * D], sm[D * D];
    int bid = blockIdx.x;
    int tid = threadIdx.x;
    if (bid < P_CVT) {
        int i = (bid * 256 + tid) * 4;
        float4 va = *(const float4*)(h_a + i);
        float4 vb = *(const float4*)(h_b + i);
        ushort4 ua = { f2bf(va.x), f2bf(va.y), f2bf(va.z), f2bf(va.w) };
        ushort4 ub = { f2bf(vb.x), f2bf(vb.y), f2bf(vb.z), f2bf(vb.w) };
        *(ushort4*)(oa + i) = ua;
        *(ushort4*)(ob + i) = ub;
        return;
    }
    bid -= P_CVT;
    if (bid < P_ZERO) {
        int i = bid * 256 + tid;
        if (i < 40000) ((int4*)cur)[i] = make_int4(0, 0, 0, 0);
        return;
    }
    bid -= P_ZERO;
    if (bid < P_PACK) {
        int n = bid;
        int t = tid >> 7, i = tid & 127;
        Wqt[(t * C + n) * C + i] = f2bf(Wq[(t * C + i) * C + n]);
        Wat[(t * C + n) * C + i] = f2bf(Wa[(t * C + i) * C + n]);
        return;
    }
    bid -= P_PACK;
    {
        int r = bid >> 3, h = bid & 7;
        int t = r >> 1;
        if (tid < D * D) {
            sa[tid] = att[(r * H + h) * D * D + tid];
            sm[tid] = msg[(r * H + h) * D * D + tid];
        }
        __syncthreads();
        int i = tid & 127;
        for (int e = (tid >> 7); e < D; e += 2) {
            float sk = 0.f, sv = 0.f;
            for (int d = 0; d < D; ++d) {
                sk += Wk[(t * C + i) * C + h * D + d] * sa[d * D + e];
                sv += Wv[(t * C + i) * C + h * D + d] * sm[d * D + e];
            }
            Wkt[(r * C + h * D + e) * C + i] = f2bf(sk);
            Wvt[(r * C + h * D + e) * C + i] = f2bf(sv);
        }
        if (tid < D) {
            int e = tid;
            float sk = 0.f, sv = 0.f;
            for (int d = 0; d < D; ++d) {
                sk += bk[t * C + h * D + d] * sa[d * D + e];
                sv += bv[t * C + h * D + d] * sm[d * D + e];
            }
            bkt[r * C + h * D + e] = sk;
            bvt[r * C + h * D + e] = sv;
        }
    }
}

// ---------------- mega: edge partition (counting-sort) || projections ----------------
// Partition as block-local counting sort: LDS histogram over 2500 8-dst
// buckets, ONE global atomic per touched bucket per block, then chunked
// 4B-record writes into reserved contiguous chunks.
__global__ __launch_bounds__(256) void mega_k(const int* __restrict__ s0, const int* __restrict__ s1,
                                              const int* __restrict__ s2, const int* __restrict__ s3,
                                              const int* __restrict__ d0, const int* __restrict__ d1,
                                              const int* __restrict__ d2, const int* __restrict__ d3,
                                              int* __restrict__ cur, unsigned int* __restrict__ part,
                                              const unsigned short* __restrict__ ha,
                                              const unsigned short* __restrict__ hb,
                                              const unsigned short* __restrict__ Wqt,
                                              const unsigned short* __restrict__ Wkt,
                                              const unsigned short* __restrict__ Wvt,
                                              const float* __restrict__ bq,
                                              const float* __restrict__ bkt,
                                              const float* __restrict__ bvt,
                                              unsigned short* __restrict__ Qa,
                                              unsigned short* __restrict__ Qb,
                                              unsigned short* __restrict__ Kall,
                                              unsigned short* __restrict__ Vall) {
    __shared__ int hcnt[BUCKETS];
    __shared__ int hbase[BUCKETS];
    int bid = blockIdx.x;
    int tid = threadIdx.x;

    if (bid < PART_BLOCKS) {
        // ---- partition path: counting-sort of 16K edges into 8-dst buckets ----
        int r  = bid & 3;
        int pb = bid >> 2;                       // 0..19
        int start = pb * PB_EDGES;
        int nval = N_EDGES - start;
        if (nval > PB_EDGES) nval = PB_EDGES;    // last block: 8704
        int nq = nval >> 2;                      // int4 count (both tails %4==0)
        const int* dd = (r == 0) ? d0 : (r == 1) ? d1 : (r == 2) ? d2 : d3;
        const int* ss = (r == 0) ? s0 : (r == 1) ? s1 : (r == 2) ? s2 : s3;
        for (int b = tid; b < BUCKETS; b += 256) hcnt[b] = 0;
        __syncthreads();
        // pass A: LDS histogram
        for (int i = tid; i < nq; i += 256) {
            int4 d4 = *(const int4*)(dd + start + i * 4);
            atomicAdd(&hcnt[d4.x >> 3], 1);
            atomicAdd(&hcnt[d4.y >> 3], 1);
            atomicAdd(&hcnt[d4.z >> 3], 1);
            atomicAdd(&hcnt[d4.w >> 3], 1);
        }
        __syncthreads();
        // reserve contiguous chunks: one global atomic per touched bucket
        for (int b = tid; b < BUCKETS; b += 256) {
            int c = hcnt[b];
            hbase[b] = c ? atomicAdd(&cur[(r * BUCKETS + b) * 16], c) : 0;
            hcnt[b] = 0;                         // reuse as pass-B cursor
        }
        __syncthreads();
        // pass B: scatter 4B records into reserved chunks
        for (int i = tid; i < nq; i += 256) {
            int4 d4 = *(const int4*)(dd + start + i * 4);
            int4 s4 = *(const int4*)(ss + start + i * 4);
            int b0 = d4.x >> 3, b1 = d4.y >> 3, b2 = d4.z >> 3, b3 = d4.w >> 3;
            int i0 = atomicAdd(&hcnt[b0], 1);
            int i1 = atomicAdd(&hcnt[b1], 1);
            int i2 = atomicAdd(&hcnt[b2], 1);
            int i3 = atomicAdd(&hcnt[b3], 1);
            int p0 = hbase[b0] + i0, p1 = hbase[b1] + i1, p2 = hbase[b2] + i2, p3 = hbase[b3] + i3;
            if (p0 < BCAP) part[(size_t)(r * BUCKETS + b0) * BCAP + p0] = (unsigned int)s4.x | ((unsigned int)(d4.x & 7) << 15);
            if (p1 < BCAP) part[(size_t)(r * BUCKETS + b1) * BCAP + p1] = (unsigned int)s4.y | ((unsigned int)(d4.y & 7) << 15);
            if (p2 < BCAP) part[(size_t)(r * BUCKETS + b2) * BCAP + p2] = (unsigned int)s4.z | ((unsigned int)(d4.z & 7) << 15);
            if (p3 < BCAP) part[(size_t)(r * BUCKETS + b3) * BCAP + p3] = (unsigned int)s4.w | ((unsigned int)(d4.w & 7) << 15);
        }
        return;
    }
    // ---- projection path: 10 jobs x 313 blocks ----
    int proj_id = bid - PART_BLOCKS;
    int j = proj_id / 313;
    int xb = proj_id - j * 313;
    const unsigned short* A;
    const unsigned short* Wt;
    const float* bias;
    unsigned short* Out;
    if (j < 2) {
        A = j ? hb : ha; Wt = Wqt + j * C * C; bias = bq + j * C; Out = j ? Qb : Qa;
    } else if (j < 6) {
        int r = j - 2;
        A = (r < 2) ? ha : hb; Wt = Wkt + r * C * C; bias = bkt + r * C;
        Out = Kall + (size_t)r * N_NODES * C;
    } else {
        int r = j - 6;
        A = (r < 2) ? ha : hb; Wt = Wvt + r * C * C; bias = bvt + r * C;
        Out = Vall + (size_t)r * N_NODES * C;
    }
    int wid = threadIdx.x >> 6, l = threadIdx.x & 63;
    int row_base = xb * 64 + wid * 16;
    int lm = l & 15, q = l >> 4;
    f32x4 acc[8] = {};
    int arow = row_base + lm;
    if (arow >= N_NODES) arow = N_NODES - 1;
    const s16x8* Ap = (const s16x8*)(A + (size_t)arow * C);
#pragma unroll
    for (int kc = 0; kc < 4; ++kc) {
        s16x8 af = Ap[kc * 4 + q];
#pragma unroll
        for (int t = 0; t < 8; ++t) {
            s16x8 bf = *(const s16x8*)(Wt + (t * 16 + lm) * C + kc * 32 + q * 8);
            acc[t] = __builtin_amdgcn_mfma_f32_16x16x32_bf16(af, bf, acc[t], 0, 0, 0);
        }
    }
#pragma unroll
    for (int t = 0; t < 8; ++t) {
        int col = t * 16 + lm;
        float b = bias[col];
#pragma unroll
        for (int i = 0; i < 4; ++i) {
            int row = row_base + q * 4 + i;
            if (row < N_NODES) Out[(size_t)row * C + col] = f2bf(acc[t][i] + b);
        }
    }
}

// ---------------- P2: bucket-scan + LDS-bin + scoring/softmax/aggregate + FUSED OUTPUT ----------------
// Main loop identical to R7. R8 lesson: the epilogue's presence alone collapses
// the gather loop's load batching (VGPR 44->72, MLP/4) — the whole-function
// scheduler hoists/mixes epilogue code into the main loop region. Fix per guide
// rules #18/#19: sched_barrier(0) fences around the region boundary + an asm
// opacity barrier on the epilogue index (Wat-load addresses become data-
// dependent on a post-barrier value -> unhoistable) + unroll-2 epilogue (small
// live footprint). Verification signal: VGPR <= ~56. Prize (measured R7 vs R8):
// final_mm + one dispatch boundary = 40 us.
__global__ __launch_bounds__(256) void node_p2(const int* __restrict__ cur,
                                               const unsigned int* __restrict__ part,
                                               const unsigned int* __restrict__ Kall,
                                               const unsigned int* __restrict__ Vall,
                                               const float* __restrict__ pri,
                                               const unsigned int* __restrict__ Qa,
                                               const unsigned int* __restrict__ Qb,
                                               const unsigned short* __restrict__ WatAll,
                                               const float* __restrict__ baAll,
                                               const float* __restrict__ skip,
                                               const float* __restrict__ h_a,
                                               const float* __restrict__ h_b,
                                               float* __restrict__ OutAll) {
    __shared__ unsigned short slot[2][4][SLOT];
    __shared__ int cnt[2][4];
    __shared__ __align__(16) float aggl[4][C];   // 4 nodes x 128 ch f32 (2 KB)
    int g = blockIdx.x;
    int xcd = g & 7, idx = g >> 3;     // round-robin XCD id, slot within XCD
    int type = xcd >> 2;               // xcd 0-3 -> type 0, xcd 4-7 -> type 1
    int range = (xcd & 3) * 1250 + idx; // 4 XCDs x 1250 = 5000 ranges per type
    int relA = type ? 1 : 0;           // ab : aa
    int relB = type ? 3 : 2;           // bb : ba
    if (threadIdx.x < 8) ((int*)cnt)[threadIdx.x] = 0;
    __syncthreads();
    int bkt = range >> 1;              // 8-dst bucket containing this range
    int w   = range & 1;               // 4-dst window within the bucket
#pragma unroll
    for (int rr = 0; rr < 2; ++rr) {
        int rel = rr ? relB : relA;
        int c = cur[(rel * BUCKETS + bkt) * 16];
        if (c > BCAP) c = BCAP;
        const unsigned int* pp = part + (size_t)(rel * BUCKETS + bkt) * BCAP;
        for (int i = threadIdx.x; i < c; i += 256) {
            unsigned int rec = pp[i];
            int dlow = (rec >> 15) & 7;
            if ((dlow >> 2) == w) {
                int dof = dlow & 3;
                int p = atomicAdd(&cnt[rr][dof], 1);
                if (p < SLOT) slot[rr][dof][p] = (unsigned short)(rec & 0x7fffu);
            }
        }
    }
    __syncthreads();

    int wid = threadIdx.x >> 6, l = threadIdx.x & 63;
    int eg = l >> 4;                    // edge-group 0..3 (4 edges in flight per wave)
    int j  = l & 15;                    // channel-lane: owns channels 8j..8j+7
    int hg = j >> 1;                    // head = 16 ch = 2 lanes
    int dof = wid;                      // ONE dst per wave
    int n = range * 4 + dof;
    const unsigned int* Q32 = type ? Qb : Qa;
    uint4 qv = *(const uint4*)(Q32 + (size_t)n * 64 + j * 4);
    float q0 = bf_lo(qv.x), q1 = bf_hi(qv.x), q2 = bf_lo(qv.y), q3 = bf_hi(qv.y);
    float q4 = bf_lo(qv.z), q5 = bf_hi(qv.z), q6 = bf_lo(qv.w), q7 = bf_hi(qv.w);
    float out[8] = {};

#pragma unroll 1
    for (int rr = 0; rr < 2; ++rr) {
        int rel = rr ? relB : relA;
        const char* Kb = (const char*)(Kall + (size_t)rel * N_NODES * 64);
        const char* Vb = (const char*)(Vall + (size_t)rel * N_NODES * 64);
        float pv = pri[rel * 8 + hg] * 0.25f;
        int deg = cnt[rr][dof];
        if (deg > SLOT) deg = SLOT;
        float m = -1e30f, sum = 0.f;
        float acc[8] = {};
        for (int base = 0; base < deg; base += 16) {   // 16 edges/chunk = 4 per edge-group
            float s[4];
            uint4 vv[4];
#pragma unroll
            for (int i = 0; i < 4; ++i) {
                int idx2 = base + i * 4 + eg;          // interleaved -> balanced tails
                float d = -1e30f;
                uint4 v = {0u, 0u, 0u, 0u};
                if (idx2 < deg) {
                    // 32-bit voffset: sv*256B row + j*16B -> sgpr-base + voffset loads
                    unsigned off = ((unsigned)slot[rr][dof][idx2] << 8) | ((unsigned)j << 4);
                    uint4 kv = *(const uint4*)(Kb + off);
                    v = *(const uint4*)(Vb + off);     // fetched with K (indep of max)
                    d = q0 * bf_lo(kv.x) + q1 * bf_hi(kv.x)
                      + q2 * bf_lo(kv.y) + q3 * bf_hi(kv.y)
                      + q4 * bf_lo(kv.z) + q5 * bf_hi(kv.z)
                      + q6 * bf_lo(kv.w) + q7 * bf_hi(kv.w);
                    d += __shfl_xor(d, 1);             // full 16-ch head dot in both lanes
                    d *= pv;
                }
                s[i] = d;
                vv[i] = v;
            }
            float mloc = fmaxf(fmaxf(s[0], s[1]), fmaxf(s[2], s[3]));
            float mnew = fmaxf(m, mloc);
            float alpha = __expf(m - mnew);            // first chunk: exp(-huge)=0
            sum *= alpha;
#pragma unroll
            for (int c2 = 0; c2 < 8; ++c2) acc[c2] *= alpha;
            m = mnew;
#pragma unroll
            for (int i = 0; i < 4; ++i) {
                // guard: an all-invalid group has m==-1e30 -> exp(0)==1 would leak
                float ww = (s[i] > -1e29f) ? __expf(s[i] - m) : 0.f;
                sum += ww;
                acc[0] += ww * bf_lo(vv[i].x); acc[1] += ww * bf_hi(vv[i].x);
                acc[2] += ww * bf_lo(vv[i].y); acc[3] += ww * bf_hi(vv[i].y);
                acc[4] += ww * bf_lo(vv[i].z); acc[5] += ww * bf_hi(vv[i].z);
                acc[6] += ww * bf_lo(vv[i].w); acc[7] += ww * bf_hi(vv[i].w);
            }
        }
        // merge the 4 edge-group partials (butterfly over lane bits 4,5):
        // global max, rescale each group's state by exp(m-m_all), plain-sum.
        float m1 = fmaxf(m, __shfl_xor(m, 16));
        float m2 = fmaxf(m1, __shfl_xor(m1, 32));
        float beta = __expf(m - m2);                   // empty group: exp(-huge)=0
        sum *= beta;
        sum += __shfl_xor(sum, 16);
        sum += __shfl_xor(sum, 32);
#pragma unroll
        for (int c2 = 0; c2 < 8; ++c2) {
            float a = acc[c2] * beta;
            a += __shfl_xor(a, 16);
            a += __shfl_xor(a, 32);
            acc[c2] = a;
        }
        if (deg > 0) {
            float rs = 1.f / sum;
#pragma unroll
            for (int c2 = 0; c2 < 8; ++c2) out[c2] += acc[c2] * rs;
        }
    }
    // ---- region fence: keep the epilogue OUT of the main loop's schedule ----
    __builtin_amdgcn_sched_barrier(0);
    // ---- stage f32 agg rows in LDS (0.5 = cross_reducer 'mean') ----
    if (eg == 0) {
#pragma unroll
        for (int c2 = 0; c2 < 8; ++c2) aggl[dof][j * 8 + c2] = 0.5f * out[c2];
    }
    __syncthreads();
    __builtin_amdgcn_sched_barrier(0);
    // ---- fused final (was final_mm): Out = al*(agg @ Wa + ba) + (1-al)*h ----
    // 512 outputs (4 nodes x 128 cols), 2 per thread; nd uniform per wave ->
    // aggl reads are LDS broadcasts; Wat rows are L2-hot (32KB per type).
    {
        const unsigned short* Wt = WatAll + type * C * C;
        const float* bat = baAll + type * C;
        const float* horig = type ? h_b : h_a;
        float* Outp = OutAll + (size_t)type * N_NODES * C;
        float al = 1.f / (1.f + __expf(-skip[type]));
#pragma unroll 1
        for (int it = 0; it < 2; ++it) {
            int e = it * 256 + threadIdx.x;
            asm volatile("" : "+v"(e));       // opacity: address unhoistable above here
            int nd = e >> 7, col = e & 127;
            int node = range * 4 + nd;
            const uint4* w4 = (const uint4*)(Wt + (size_t)col * C);  // Wat row col = Wa col
            const float4* ag4 = (const float4*)aggl[nd];
            float acc = 0.f;
#pragma unroll 2
            for (int kc = 0; kc < 16; ++kc) {
                uint4 wv = w4[kc];
                float4 a0 = ag4[kc * 2];
                float4 a1 = ag4[kc * 2 + 1];
                acc += a0.x * bf_lo(wv.x) + a0.y * bf_hi(wv.x)
                     + a0.z * bf_lo(wv.y) + a0.w * bf_hi(wv.y)
                     + a1.x * bf_lo(wv.z) + a1.y * bf_hi(wv.z)
                     + a1.z * bf_lo(wv.w) + a1.w * bf_hi(wv.w);
            }
            Outp[(size_t)node * C + col] =
                al * (acc + bat[col]) + (1.f - al) * horig[(size_t)node * C + col];
        }
    }
}

extern "C" void kernel_launch(void* const* d_in, const int* in_sizes, int n_in,
                              void* d_out, int out_size, void* d_ws, size_t ws_size,
                              hipStream_t stream) {
    const float* h_a  = (const float*)d_in[0];
    const float* h_b  = (const float*)d_in[1];
    const float* Wk   = (const float*)d_in[2];
    const float* bk   = (const float*)d_in[3];
    const float* Wq   = (const float*)d_in[4];
    const float* bq   = (const float*)d_in[5];
    const float* Wv   = (const float*)d_in[6];
    const float* bv   = (const float*)d_in[7];
    const float* Wa   = (const float*)d_in[8];
    const float* ba   = (const float*)d_in[9];
    const float* att  = (const float*)d_in[10];
    const float* msg  = (const float*)d_in[11];
    const float* pri  = (const float*)d_in[12];
    const float* skip = (const float*)d_in[13];
    const int* srcs[4] = {(const int*)d_in[14], (const int*)d_in[16], (const int*)d_in[18], (const int*)d_in[20]};
    const int* dsts[4] = {(const int*)d_in[15], (const int*)d_in[17], (const int*)d_in[19], (const int*)d_in[21]};
    float* out = (float*)d_out;

    char* w = (char*)d_ws;
    auto alloc = [&](size_t bytes) {
        char* p = w;
        w += (bytes + 255) & ~(size_t)255;
        return p;
    };
    unsigned short* ha_bf = (unsigned short*)alloc((size_t)N_NODES * C * 2);
    unsigned short* hb_bf = (unsigned short*)alloc((size_t)N_NODES * C * 2);
    unsigned short* Qa    = (unsigned short*)alloc((size_t)N_NODES * C * 2);
    unsigned short* Qb    = (unsigned short*)alloc((size_t)N_NODES * C * 2);
    unsigned short* Kall  = (unsigned short*)alloc((size_t)4 * N_NODES * C * 2);
    unsigned short* Vall  = (unsigned short*)alloc((size_t)4 * N_NODES * C * 2);
    unsigned short* Wqt   = (unsigned short*)alloc(2 * C * C * 2);
    unsigned short* Wat   = (unsigned short*)alloc(2 * C * C * 2);
    unsigned short* Wkt   = (unsigned short*)alloc(4 * C * C * 2);
    unsigned short* Wvt   = (unsigned short*)alloc(4 * C * C * 2);
    float* bkt            = (float*)alloc(4 * C * 4);
    float* bvt            = (float*)alloc(4 * C * 4);
    int* cur              = (int*)alloc((size_t)4 * BUCKETS * 16 * 4);
    unsigned int* part    = (unsigned int*)alloc((size_t)4 * BUCKETS * BCAP * 4);

    // 1) fused prep: cvt + zero-cursors + pack + fuse
    prep_k<<<P_CVT + P_ZERO + P_PACK + P_FUSE, 256, 0, stream>>>(
        h_a, h_b, ha_bf, hb_bf, Wq, Wa, Wqt, Wat,
        Wk, Wv, bk, bv, att, msg, Wkt, Wvt, bkt, bvt, cur);

    // 2) fused partition (counting-sort) || projections
    mega_k<<<MB_TOTAL, 256, 0, stream>>>(
        srcs[0], srcs[1], srcs[2], srcs[3],
        dsts[0], dsts[1], dsts[2], dsts[3],
        cur, part,
        ha_bf, hb_bf, Wqt, Wkt, Wvt, bq, bkt, bvt,
        Qa, Qb, Kall, Vall);

    // 3) fused scoring + softmax + aggregate + OUTPUT PROJECTION (final_mm fused)
    node_p2<<<2 * NRANGE, 256, 0, stream>>>(cur, part,
                                            (const unsigned int*)Kall, (const unsigned int*)Vall,
                                            pri,
                                            (const unsigned int*)Qa, (const unsigned int*)Qb,
                                            Wat, ba, skip, h_a, h_b, out);
}

// Round 11
// 304.398 us; speedup vs baseline: 1.8245x; 1.2928x over previous
//
#include <hip/hip_runtime.h>
#include <stdint.h>

#define N_NODES 20000
#define N_EDGES 320000
#define C 128
#define H 8
#define D 16
#define SLOT 64        // max degree per node per relation (Poisson(16); P(>=64)~1e-18, guarded)
#define NRANGE 5000    // node_p2 ranges of 4 dsts
#define BUCKETS 2500   // 8-dst buckets per relation (20000/8)
#define BCAP 224       // records per (rel,bucket); mean 128, sigma 11.3, P(>224)~1e-13, guarded

// prep_k job partition (block ranges)
#define P_CVT 2500     // 2500*256*4 == N_NODES*C
#define P_ZERO 157     // 4*2500*16 ints = 160000 ints = 40000 int4
#define P_PACK 128
#define P_FUSE 32
// mega_k: 80 part blocks (16K edges each, counting-sort) + 3130 proj blocks.
#define PB_EDGES 16384
#define PART_BLOCKS 80
#define PROJ_BLOCKS 3130
#define MB_TOTAL (PART_BLOCKS + PROJ_BLOCKS)

typedef short s16x8 __attribute__((ext_vector_type(8)));
typedef float f32x4 __attribute__((ext_vector_type(4)));

__device__ __forceinline__ unsigned short f2bf(float f) {
    unsigned int b = __float_as_uint(f);
    b += 0x7fffu + ((b >> 16) & 1u);
    return (unsigned short)(b >> 16);
}
__device__ __forceinline__ float bf2f(unsigned int u) {
    return __uint_as_float(u << 16);
}
__device__ __forceinline__ float bf_lo(unsigned int u) {   // low bf16 of a dword -> f32 (1 instr)
    return __uint_as_float(u << 16);
}
__device__ __forceinline__ float bf_hi(unsigned int u) {   // high bf16 of a dword -> f32 (1 instr)
    return __uint_as_float(u & 0xffff0000u);
}

// ---------------- prep: cvt_h + zero-cursors + pack_wt + fuse_w in ONE dispatch ----------------
__global__ __launch_bounds__(256) void prep_k(const float* __restrict__ h_a, const float* __restrict__ h_b,
                                              unsigned short* __restrict__ oa, unsigned short* __restrict__ ob,
                                              const float* __restrict__ Wq, const float* __restrict__ Wa,
                                              unsigned short* __restrict__ Wqt, unsigned short* __restrict__ Wat,
                                              const float* __restrict__ Wk, const float* __restrict__ Wv,
                                              const float* __restrict__ bk, const float* __restrict__ bv,
                                              const float* __restrict__ att, const float* __restrict__ msg,
                                              unsigned short* __restrict__ Wkt, unsigned short* __restrict__ Wvt,
                                              float* __restrict__ bkt, float* __restrict__ bvt,
                                              int* __restrict__ cur) {
    __shared__ float sa[D * D], sm[D * D];
    int bid = blockIdx.x;
    int tid = threadIdx.x;
    if (bid < P_CVT) {
        int i = (bid * 256 + tid) * 4;
        float4 va = *(const float4*)(h_a + i);
        float4 vb = *(const float4*)(h_b + i);
        ushort4 ua = { f2bf(va.x), f2bf(va.y), f2bf(va.z), f2bf(va.w) };
        ushort4 ub = { f2bf(vb.x), f2bf(vb.y), f2bf(vb.z), f2bf(vb.w) };
        *(ushort4*)(oa + i) = ua;
        *(ushort4*)(ob + i) = ub;
        return;
    }
    bid -= P_CVT;
    if (bid < P_ZERO) {
        int i = bid * 256 + tid;
        if (i < 40000) ((int4*)cur)[i] = make_int4(0, 0, 0, 0);
        return;
    }
    bid -= P_ZERO;
    if (bid < P_PACK) {
        int n = bid;
        int t = tid >> 7, i = tid & 127;
        Wqt[(t * C + n) * C + i] = f2bf(Wq[(t * C + i) * C + n]);
        Wat[(t * C + n) * C + i] = f2bf(Wa[(t * C + i) * C + n]);
        return;
    }
    bid -= P_PACK;
    {
        int r = bid >> 3, h = bid & 7;
        int t = r >> 1;
        if (tid < D * D) {
            sa[tid] = att[(r * H + h) * D * D + tid];
            sm[tid] = msg[(r * H + h) * D * D + tid];
        }
        __syncthreads();
        int i = tid & 127;
        for (int e = (tid >> 7); e < D; e += 2) {
            float sk = 0.f, sv = 0.f;
            for (int d = 0; d < D; ++d) {
                sk += Wk[(t * C + i) * C + h * D + d] * sa[d * D + e];
                sv += Wv[(t * C + i) * C + h * D + d] * sm[d * D + e];
            }
            Wkt[(r * C + h * D + e) * C + i] = f2bf(sk);
            Wvt[(r * C + h * D + e) * C + i] = f2bf(sv);
        }
        if (tid < D) {
            int e = tid;
            float sk = 0.f, sv = 0.f;
            for (int d = 0; d < D; ++d) {
                sk += bk[t * C + h * D + d] * sa[d * D + e];
                sv += bv[t * C + h * D + d] * sm[d * D + e];
            }
            bkt[r * C + h * D + e] = sk;
            bvt[r * C + h * D + e] = sv;
        }
    }
}

// ---------------- mega: edge partition (counting-sort) || projections ----------------
// Partition as block-local counting sort: LDS histogram over 2500 8-dst
// buckets, ONE global atomic per touched bucket per block, then chunked
// 4B-record writes into reserved contiguous chunks.
__global__ __launch_bounds__(256) void mega_k(const int* __restrict__ s0, const int* __restrict__ s1,
                                              const int* __restrict__ s2, const int* __restrict__ s3,
                                              const int* __restrict__ d0, const int* __restrict__ d1,
                                              const int* __restrict__ d2, const int* __restrict__ d3,
                                              int* __restrict__ cur, unsigned int* __restrict__ part,
                                              const unsigned short* __restrict__ ha,
                                              const unsigned short* __restrict__ hb,
                                              const unsigned short* __restrict__ Wqt,
                                              const unsigned short* __restrict__ Wkt,
                                              const unsigned short* __restrict__ Wvt,
                                              const float* __restrict__ bq,
                                              const float* __restrict__ bkt,
                                              const float* __restrict__ bvt,
                                              unsigned short* __restrict__ Qa,
                                              unsigned short* __restrict__ Qb,
                                              unsigned short* __restrict__ Kall,
                                              unsigned short* __restrict__ Vall) {
    __shared__ int hcnt[BUCKETS];
    __shared__ int hbase[BUCKETS];
    int bid = blockIdx.x;
    int tid = threadIdx.x;

    if (bid < PART_BLOCKS) {
        // ---- partition path: counting-sort of 16K edges into 8-dst buckets ----
        int r  = bid & 3;
        int pb = bid >> 2;                       // 0..19
        int start = pb * PB_EDGES;
        int nval = N_EDGES - start;
        if (nval > PB_EDGES) nval = PB_EDGES;    // last block: 8704
        int nq = nval >> 2;                      // int4 count (both tails %4==0)
        const int* dd = (r == 0) ? d0 : (r == 1) ? d1 : (r == 2) ? d2 : d3;
        const int* ss = (r == 0) ? s0 : (r == 1) ? s1 : (r == 2) ? s2 : s3;
        for (int b = tid; b < BUCKETS; b += 256) hcnt[b] = 0;
        __syncthreads();
        // pass A: LDS histogram
        for (int i = tid; i < nq; i += 256) {
            int4 d4 = *(const int4*)(dd + start + i * 4);
            atomicAdd(&hcnt[d4.x >> 3], 1);
            atomicAdd(&hcnt[d4.y >> 3], 1);
            atomicAdd(&hcnt[d4.z >> 3], 1);
            atomicAdd(&hcnt[d4.w >> 3], 1);
        }
        __syncthreads();
        // reserve contiguous chunks: one global atomic per touched bucket
        for (int b = tid; b < BUCKETS; b += 256) {
            int c = hcnt[b];
            hbase[b] = c ? atomicAdd(&cur[(r * BUCKETS + b) * 16], c) : 0;
            hcnt[b] = 0;                         // reuse as pass-B cursor
        }
        __syncthreads();
        // pass B: scatter 4B records into reserved chunks
        for (int i = tid; i < nq; i += 256) {
            int4 d4 = *(const int4*)(dd + start + i * 4);
            int4 s4 = *(const int4*)(ss + start + i * 4);
            int b0 = d4.x >> 3, b1 = d4.y >> 3, b2 = d4.z >> 3, b3 = d4.w >> 3;
            int i0 = atomicAdd(&hcnt[b0], 1);
            int i1 = atomicAdd(&hcnt[b1], 1);
            int i2 = atomicAdd(&hcnt[b2], 1);
            int i3 = atomicAdd(&hcnt[b3], 1);
            int p0 = hbase[b0] + i0, p1 = hbase[b1] + i1, p2 = hbase[b2] + i2, p3 = hbase[b3] + i3;
            if (p0 < BCAP) part[(size_t)(r * BUCKETS + b0) * BCAP + p0] = (unsigned int)s4.x | ((unsigned int)(d4.x & 7) << 15);
            if (p1 < BCAP) part[(size_t)(r * BUCKETS + b1) * BCAP + p1] = (unsigned int)s4.y | ((unsigned int)(d4.y & 7) << 15);
            if (p2 < BCAP) part[(size_t)(r * BUCKETS + b2) * BCAP + p2] = (unsigned int)s4.z | ((unsigned int)(d4.z & 7) << 15);
            if (p3 < BCAP) part[(size_t)(r * BUCKETS + b3) * BCAP + p3] = (unsigned int)s4.w | ((unsigned int)(d4.w & 7) << 15);
        }
        return;
    }
    // ---- projection path: 10 jobs x 313 blocks ----
    int proj_id = bid - PART_BLOCKS;
    int j = proj_id / 313;
    int xb = proj_id - j * 313;
    const unsigned short* A;
    const unsigned short* Wt;
    const float* bias;
    unsigned short* Out;
    if (j < 2) {
        A = j ? hb : ha; Wt = Wqt + j * C * C; bias = bq + j * C; Out = j ? Qb : Qa;
    } else if (j < 6) {
        int r = j - 2;
        A = (r < 2) ? ha : hb; Wt = Wkt + r * C * C; bias = bkt + r * C;
        Out = Kall + (size_t)r * N_NODES * C;
    } else {
        int r = j - 6;
        A = (r < 2) ? ha : hb; Wt = Wvt + r * C * C; bias = bvt + r * C;
        Out = Vall + (size_t)r * N_NODES * C;
    }
    int wid = threadIdx.x >> 6, l = threadIdx.x & 63;
    int row_base = xb * 64 + wid * 16;
    int lm = l & 15, q = l >> 4;
    f32x4 acc[8] = {};
    int arow = row_base + lm;
    if (arow >= N_NODES) arow = N_NODES - 1;
    const s16x8* Ap = (const s16x8*)(A + (size_t)arow * C);
#pragma unroll
    for (int kc = 0; kc < 4; ++kc) {
        s16x8 af = Ap[kc * 4 + q];
#pragma unroll
        for (int t = 0; t < 8; ++t) {
            s16x8 bf = *(const s16x8*)(Wt + (t * 16 + lm) * C + kc * 32 + q * 8);
            acc[t] = __builtin_amdgcn_mfma_f32_16x16x32_bf16(af, bf, acc[t], 0, 0, 0);
        }
    }
#pragma unroll
    for (int t = 0; t < 8; ++t) {
        int col = t * 16 + lm;
        float b = bias[col];
#pragma unroll
        for (int i = 0; i < 4; ++i) {
            int row = row_base + q * 4 + i;
            if (row < N_NODES) Out[(size_t)row * C + col] = f2bf(acc[t][i] + b);
        }
    }
}

// ---------------- final: out = al*(agg @ Wa + ba) + (1-al)*h ; both types via blockIdx.y ----------------
// R10 re-tile: was 313x2 blocks x 64 rows (2504 waves = 2.4/SIMD, latency-starved
// ~30us). Now COLUMN-SPLIT: block = 16 rows x 128 cols, 4 waves each computing
// 16x32 (2 t-tiles). Grid (1250,2) -> 10000 waves (4x parallelism). A-fragments
// read 4x redundantly (+30MB L2/L3-hot, latency-hidden). Same MFMA mapping and
// numerics; 1250*16==20000 so no row guards.
__global__ __launch_bounds__(256) void final_mm(const unsigned short* __restrict__ AggAll,
                                                const unsigned short* __restrict__ WatAll,
                                                const float* __restrict__ baAll,
                                                const float* __restrict__ skip,
                                                const float* __restrict__ h_a,
                                                const float* __restrict__ h_b,
                                                float* __restrict__ OutAll) {
    int ty = blockIdx.y;
    const unsigned short* Agg = AggAll + (size_t)ty * N_NODES * C;
    const unsigned short* Wat = WatAll + ty * C * C;
    const float* ba = baAll + ty * C;
    const float* h_orig = ty ? h_b : h_a;
    float* Out = OutAll + (size_t)ty * N_NODES * C;
    int wid = threadIdx.x >> 6, l = threadIdx.x & 63;
    int row_base = blockIdx.x * 16;
    int lm = l & 15, q = l >> 4;
    f32x4 acc[2] = {};
    int arow = row_base + lm;                    // < 20000 always
    const s16x8* Ap = (const s16x8*)(Agg + (size_t)arow * C);
#pragma unroll
    for (int kc = 0; kc < 4; ++kc) {
        s16x8 af = Ap[kc * 4 + q];
#pragma unroll
        for (int tt = 0; tt < 2; ++tt) {
            int t = wid * 2 + tt;
            s16x8 bf = *(const s16x8*)(Wat + (t * 16 + lm) * C + kc * 32 + q * 8);
            acc[tt] = __builtin_amdgcn_mfma_f32_16x16x32_bf16(af, bf, acc[tt], 0, 0, 0);
        }
    }
    float al = 1.f / (1.f + __expf(-skip[ty]));
#pragma unroll
    for (int tt = 0; tt < 2; ++tt) {
        int col = (wid * 2 + tt) * 16 + lm;
        float b = ba[col];
#pragma unroll
        for (int i = 0; i < 4; ++i) {
            int row = row_base + q * 4 + i;
            Out[(size_t)row * C + col] = al * (acc[tt][i] + b) + (1.f - al) * h_orig[(size_t)row * C + col];
        }
    }
}

// ---------------- P2: bucket-scan + LDS-bin + fused scoring/softmax/aggregate ----------------
// R7 structure verbatim (fusion line R6/R8/R9 abandoned: epilogue presence makes
// the pressure-aware scheduler serialize the gather loop's loads — unfixable at
// HIP level). One block per (type, 4 dsts); ONE dst per wave; 4 edge-groups of
// 16 lanes, 8 ch/lane, dwordx4 gathers; XCD type-partitioned grid.
__global__ __launch_bounds__(256) void node_p2(const int* __restrict__ cur,
                                               const unsigned int* __restrict__ part,
                                               const unsigned int* __restrict__ Kall,
                                               const unsigned int* __restrict__ Vall,
                                               const float* __restrict__ pri,
                                               const unsigned int* __restrict__ Qa,
                                               const unsigned int* __restrict__ Qb,
                                               unsigned int* __restrict__ agg) {
    __shared__ unsigned short slot[2][4][SLOT];
    __shared__ int cnt[2][4];
    int g = blockIdx.x;
    int xcd = g & 7, idx = g >> 3;     // round-robin XCD id, slot within XCD
    int type = xcd >> 2;               // xcd 0-3 -> type 0, xcd 4-7 -> type 1
    int range = (xcd & 3) * 1250 + idx; // 4 XCDs x 1250 = 5000 ranges per type
    int relA = type ? 1 : 0;           // ab : aa
    int relB = type ? 3 : 2;           // bb : ba
    if (threadIdx.x < 8) ((int*)cnt)[threadIdx.x] = 0;
    __syncthreads();
    int bkt = range >> 1;              // 8-dst bucket containing this range
    int w   = range & 1;               // 4-dst window within the bucket
#pragma unroll
    for (int rr = 0; rr < 2; ++rr) {
        int rel = rr ? relB : relA;
        int c = cur[(rel * BUCKETS + bkt) * 16];
        if (c > BCAP) c = BCAP;
        const unsigned int* pp = part + (size_t)(rel * BUCKETS + bkt) * BCAP;
        for (int i = threadIdx.x; i < c; i += 256) {
            unsigned int rec = pp[i];
            int dlow = (rec >> 15) & 7;
            if ((dlow >> 2) == w) {
                int dof = dlow & 3;
                int p = atomicAdd(&cnt[rr][dof], 1);
                if (p < SLOT) slot[rr][dof][p] = (unsigned short)(rec & 0x7fffu);
            }
        }
    }
    __syncthreads();

    int wid = threadIdx.x >> 6, l = threadIdx.x & 63;
    int eg = l >> 4;                    // edge-group 0..3 (4 edges in flight per wave)
    int j  = l & 15;                    // channel-lane: owns channels 8j..8j+7
    int hg = j >> 1;                    // head = 16 ch = 2 lanes
    int dof = wid;                      // ONE dst per wave
    int n = range * 4 + dof;
    const unsigned int* Q32 = type ? Qb : Qa;
    uint4 qv = *(const uint4*)(Q32 + (size_t)n * 64 + j * 4);
    float q0 = bf_lo(qv.x), q1 = bf_hi(qv.x), q2 = bf_lo(qv.y), q3 = bf_hi(qv.y);
    float q4 = bf_lo(qv.z), q5 = bf_hi(qv.z), q6 = bf_lo(qv.w), q7 = bf_hi(qv.w);
    float out[8] = {};

#pragma unroll 1
    for (int rr = 0; rr < 2; ++rr) {
        int rel = rr ? relB : relA;
        const char* Kb = (const char*)(Kall + (size_t)rel * N_NODES * 64);
        const char* Vb = (const char*)(Vall + (size_t)rel * N_NODES * 64);
        float pv = pri[rel * 8 + hg] * 0.25f;
        int deg = cnt[rr][dof];
        if (deg > SLOT) deg = SLOT;
        float m = -1e30f, sum = 0.f;
        float acc[8] = {};
        for (int base = 0; base < deg; base += 16) {   // 16 edges/chunk = 4 per edge-group
            float s[4];
            uint4 vv[4];
#pragma unroll
            for (int i = 0; i < 4; ++i) {
                int idx2 = base + i * 4 + eg;          // interleaved -> balanced tails
                float d = -1e30f;
                uint4 v = {0u, 0u, 0u, 0u};
                if (idx2 < deg) {
                    // 32-bit voffset: sv*256B row + j*16B -> sgpr-base + voffset loads
                    unsigned off = ((unsigned)slot[rr][dof][idx2] << 8) | ((unsigned)j << 4);
                    uint4 kv = *(const uint4*)(Kb + off);
                    v = *(const uint4*)(Vb + off);     // fetched with K (indep of max)
                    d = q0 * bf_lo(kv.x) + q1 * bf_hi(kv.x)
                      + q2 * bf_lo(kv.y) + q3 * bf_hi(kv.y)
                      + q4 * bf_lo(kv.z) + q5 * bf_hi(kv.z)
                      + q6 * bf_lo(kv.w) + q7 * bf_hi(kv.w);
                    d += __shfl_xor(d, 1);             // full 16-ch head dot in both lanes
                    d *= pv;
                }
                s[i] = d;
                vv[i] = v;
            }
            float mloc = fmaxf(fmaxf(s[0], s[1]), fmaxf(s[2], s[3]));
            float mnew = fmaxf(m, mloc);
            float alpha = __expf(m - mnew);            // first chunk: exp(-huge)=0
            sum *= alpha;
#pragma unroll
            for (int c2 = 0; c2 < 8; ++c2) acc[c2] *= alpha;
            m = mnew;
#pragma unroll
            for (int i = 0; i < 4; ++i) {
                // guard: an all-invalid group has m==-1e30 -> exp(0)==1 would leak
                float ww = (s[i] > -1e29f) ? __expf(s[i] - m) : 0.f;
                sum += ww;
                acc[0] += ww * bf_lo(vv[i].x); acc[1] += ww * bf_hi(vv[i].x);
                acc[2] += ww * bf_lo(vv[i].y); acc[3] += ww * bf_hi(vv[i].y);
                acc[4] += ww * bf_lo(vv[i].z); acc[5] += ww * bf_hi(vv[i].z);
                acc[6] += ww * bf_lo(vv[i].w); acc[7] += ww * bf_hi(vv[i].w);
            }
        }
        // merge the 4 edge-group partials (butterfly over lane bits 4,5):
        // global max, rescale each group's state by exp(m-m_all), plain-sum.
        float m1 = fmaxf(m, __shfl_xor(m, 16));
        float m2 = fmaxf(m1, __shfl_xor(m1, 32));
        float beta = __expf(m - m2);                   // empty group: exp(-huge)=0
        sum *= beta;
        sum += __shfl_xor(sum, 16);
        sum += __shfl_xor(sum, 32);
#pragma unroll
        for (int c2 = 0; c2 < 8; ++c2) {
            float a = acc[c2] * beta;
            a += __shfl_xor(a, 16);
            a += __shfl_xor(a, 32);
            acc[c2] = a;
        }
        if (deg > 0) {
            float rs = 1.f / sum;
#pragma unroll
            for (int c2 = 0; c2 < 8; ++c2) out[c2] += acc[c2] * rs;
        }
    }
    // 0.5 = cross_reducer 'mean'; agg stored bf16-packed. All groups hold the
    // full result for their channels; group 0 writes one dwordx4 per lane.
    if (eg == 0) {
        uint4 pk;
        pk.x = (unsigned int)f2bf(0.5f * out[0]) | ((unsigned int)f2bf(0.5f * out[1]) << 16);
        pk.y = (unsigned int)f2bf(0.5f * out[2]) | ((unsigned int)f2bf(0.5f * out[3]) << 16);
        pk.z = (unsigned int)f2bf(0.5f * out[4]) | ((unsigned int)f2bf(0.5f * out[5]) << 16);
        pk.w = (unsigned int)f2bf(0.5f * out[6]) | ((unsigned int)f2bf(0.5f * out[7]) << 16);
        *(uint4*)(agg + ((size_t)type * N_NODES + n) * 64 + j * 4) = pk;
    }
}

extern "C" void kernel_launch(void* const* d_in, const int* in_sizes, int n_in,
                              void* d_out, int out_size, void* d_ws, size_t ws_size,
                              hipStream_t stream) {
    const float* h_a  = (const float*)d_in[0];
    const float* h_b  = (const float*)d_in[1];
    const float* Wk   = (const float*)d_in[2];
    const float* bk   = (const float*)d_in[3];
    const float* Wq   = (const float*)d_in[4];
    const float* bq   = (const float*)d_in[5];
    const float* Wv   = (const float*)d_in[6];
    const float* bv   = (const float*)d_in[7];
    const float* Wa   = (const float*)d_in[8];
    const float* ba   = (const float*)d_in[9];
    const float* att  = (const float*)d_in[10];
    const float* msg  = (const float*)d_in[11];
    const float* pri  = (const float*)d_in[12];
    const float* skip = (const float*)d_in[13];
    const int* srcs[4] = {(const int*)d_in[14], (const int*)d_in[16], (const int*)d_in[18], (const int*)d_in[20]};
    const int* dsts[4] = {(const int*)d_in[15], (const int*)d_in[17], (const int*)d_in[19], (const int*)d_in[21]};
    float* out = (float*)d_out;

    char* w = (char*)d_ws;
    auto alloc = [&](size_t bytes) {
        char* p = w;
        w += (bytes + 255) & ~(size_t)255;
        return p;
    };
    unsigned short* ha_bf = (unsigned short*)alloc((size_t)N_NODES * C * 2);
    unsigned short* hb_bf = (unsigned short*)alloc((size_t)N_NODES * C * 2);
    unsigned short* Qa    = (unsigned short*)alloc((size_t)N_NODES * C * 2);
    unsigned short* Qb    = (unsigned short*)alloc((size_t)N_NODES * C * 2);
    unsigned short* Kall  = (unsigned short*)alloc((size_t)4 * N_NODES * C * 2);
    unsigned short* Vall  = (unsigned short*)alloc((size_t)4 * N_NODES * C * 2);
    unsigned short* Wqt   = (unsigned short*)alloc(2 * C * C * 2);
    unsigned short* Wat   = (unsigned short*)alloc(2 * C * C * 2);
    unsigned short* Wkt   = (unsigned short*)alloc(4 * C * C * 2);
    unsigned short* Wvt   = (unsigned short*)alloc(4 * C * C * 2);
    float* bkt            = (float*)alloc(4 * C * 4);
    float* bvt            = (float*)alloc(4 * C * 4);
    int* cur              = (int*)alloc((size_t)4 * BUCKETS * 16 * 4);
    unsigned int* part    = (unsigned int*)alloc((size_t)4 * BUCKETS * BCAP * 4);
    unsigned short* agg   = (unsigned short*)alloc((size_t)2 * N_NODES * C * 2);

    // 1) fused prep: cvt + zero-cursors + pack + fuse
    prep_k<<<P_CVT + P_ZERO + P_PACK + P_FUSE, 256, 0, stream>>>(
        h_a, h_b, ha_bf, hb_bf, Wq, Wa, Wqt, Wat,
        Wk, Wv, bk, bv, att, msg, Wkt, Wvt, bkt, bvt, cur);

    // 2) fused partition (counting-sort) || projections
    mega_k<<<MB_TOTAL, 256, 0, stream>>>(
        srcs[0], srcs[1], srcs[2], srcs[3],
        dsts[0], dsts[1], dsts[2], dsts[3],
        cur, part,
        ha_bf, hb_bf, Wqt, Wkt, Wvt, bq, bkt, bvt,
        Qa, Qb, Kall, Vall);

    // 3) fused scoring + softmax + aggregate; 1 dst per wave, XCD type-partitioned
    node_p2<<<2 * NRANGE, 256, 0, stream>>>(cur, part,
                                            (const unsigned int*)Kall, (const unsigned int*)Vall,
                                            pri,
                                            (const unsigned int*)Qa, (const unsigned int*)Qb,
                                            (unsigned int*)agg);

    // 4) final skip-gated output, both types (col-split re-tile: 4x wave parallelism)
    final_mm<<<dim3(1250, 2), 256, 0, stream>>>(agg, Wat, ba, skip, h_a, h_b, out);
}